// Round 8
// baseline (8167.387 us; speedup 1.0000x reference)
//
#include <hip/hip_runtime.h>
#include <math.h>

#define N_NODES 100000
#define N_EDGES 1600000
#define IN_C 128
#define HID_C 128
#define OUT_C 64
#define NLAYERS 4
#define KSTEPS 10
#define ALPHA 0.1f
#define LN_EPS 1e-5f

// Chunked edge layout: 16 src-chunks of 6250 nodes (1.6 MB of bf16 z each).
#define NCHUNK 16
#define CHUNK_DIV 6250
#define M2 (NCHUNK * N_NODES)            // 1,600,000 sub-segments
#define S2_N (M2 + 1)
#define S2_BLOCKS ((S2_N + 1023) / 1024) // 1563

// Persistent prop: 25 nodes per wave, 4000 waves = one resident cohort.
#define NPW 25
#define PROP_BLOCKS 1000                 // x 4 waves = 4000 = N_NODES/NPW

__device__ __forceinline__ float gelu_exact(float x) {
    return 0.5f * x * (1.0f + erff(x * 0.70710678118654752f));
}
__device__ __forceinline__ unsigned pack_bf16_rne(float a, float b) {
    unsigned ua = __float_as_uint(a);
    unsigned ub = __float_as_uint(b);
    ua = (ua + 0x7fffu + ((ua >> 16) & 1u)) >> 16;
    ub = (ub + 0x7fffu + ((ub >> 16) & 1u)) >> 16;
    return (ub << 16) | ua;
}
__device__ __forceinline__ float bf_lo(unsigned d) { return __uint_as_float(d << 16); }
__device__ __forceinline__ float bf_hi(unsigned d) { return __uint_as_float(d & 0xffff0000u); }

// ---------------------------------------------------------------------------
// count2: per-(chunk,dst) edge counts. idx = chunk(src)*N_NODES + dst.
__global__ void count2_k(const int* __restrict__ src, const int* __restrict__ dst,
                         int* __restrict__ cnt2) {
    int e = blockIdx.x * blockDim.x + threadIdx.x;
    if (e >= N_EDGES) return;
    int c = src[e] / CHUNK_DIV;
    atomicAdd(&cnt2[c * N_NODES + dst[e]], 1);
}

// scan1: per-block sums over S2_N padded values
__global__ __launch_bounds__(1024) void scan1_k(const int* __restrict__ cnt2,
                                                int* __restrict__ bsum) {
    __shared__ int s[1024];
    int i = blockIdx.x * 1024 + threadIdx.x;
    int c = (i < M2) ? cnt2[i] : 0;
    s[threadIdx.x] = c;
    __syncthreads();
    for (int off = 512; off; off >>= 1) {
        if (threadIdx.x < off) s[threadIdx.x] += s[threadIdx.x + off];
        __syncthreads();
    }
    if (threadIdx.x == 0) bsum[blockIdx.x] = s[0];
}

// scan2: exclusive scan of S2_BLOCKS (1563) block sums; 1 block, 2 elems/thread
__global__ __launch_bounds__(1024) void scan2_k(int* __restrict__ bsum) {
    __shared__ int s[1024];
    int t = threadIdx.x;
    int a = (2 * t     < S2_BLOCKS) ? bsum[2 * t]     : 0;
    int b = (2 * t + 1 < S2_BLOCKS) ? bsum[2 * t + 1] : 0;
    int tot = a + b;
    s[t] = tot;
    __syncthreads();
    for (int off = 1; off < 1024; off <<= 1) {
        int v = (t >= off) ? s[t - off] : 0;
        __syncthreads();
        s[t] += v;
        __syncthreads();
    }
    int excl = s[t] - tot;
    if (2 * t     < S2_BLOCKS) bsum[2 * t]     = excl;
    if (2 * t + 1 < S2_BLOCKS) bsum[2 * t + 1] = excl + a;
}

// scan3: per-block exclusive scan + block offset -> off2 / fill2
__global__ __launch_bounds__(1024) void scan3_k(const int* __restrict__ cnt2,
                                                const int* __restrict__ bsum,
                                                int* __restrict__ off2,
                                                int* __restrict__ fill2) {
    __shared__ int s[1024];
    int i = blockIdx.x * 1024 + threadIdx.x;
    int c = (i < M2) ? cnt2[i] : 0;
    s[threadIdx.x] = c;
    __syncthreads();
    for (int off = 1; off < 1024; off <<= 1) {
        int v = (threadIdx.x >= off) ? s[threadIdx.x - off] : 0;
        __syncthreads();
        s[threadIdx.x] += v;
        __syncthreads();
    }
    if (i <= M2) {
        int excl = s[threadIdx.x] - c + bsum[blockIdx.x];
        off2[i] = excl;
        fill2[i] = excl;
    }
}

// bucket2: scatter edges into (chunk,dst)-major segments.
// ep entry: (src*64 [dword row offset], (1-alpha)*w fp32 bits)
__global__ void bucket2_k(const int* __restrict__ src, const int* __restrict__ dst,
                          const float* __restrict__ w, int* __restrict__ fill2,
                          int2* __restrict__ ep) {
    int e = blockIdx.x * blockDim.x + threadIdx.x;
    if (e >= N_EDGES) return;
    int sv = src[e];
    int c = sv / CHUNK_DIV;
    int pos = atomicAdd(&fill2[c * N_NODES + dst[e]], 1);
    ep[pos] = make_int2(sv << 6, __float_as_int((1.0f - ALPHA) * w[e]));
}

// ---------------------------------------------------------------------------
// Encoder: H(bf16) = gelu(LN(x @ Wenc^T)).  (proven R5 structure)
__global__ __launch_bounds__(1024) void encoder_k(
        const float* __restrict__ x, const float* __restrict__ Wenc,
        const float* __restrict__ gamma, const float* __restrict__ beta,
        unsigned* __restrict__ H) {
    __shared__ float WT[IN_C * 130];
    __shared__ float XS[16][512];
    for (int i = threadIdx.x; i < IN_C * HID_C; i += 1024) {
        int c = i >> 7, k = i & 127;
        WT[k * 130 + c] = Wenc[i];
    }
    __syncthreads();
    int lane = threadIdx.x & 63;
    int wid  = threadIdx.x >> 6;
    const float2* WT2 = (const float2*)WT;
    float2 gb = ((const float2*)gamma)[lane];
    float2 bb = ((const float2*)beta)[lane];
    int wstride = gridDim.x * 16;
    float* xs = XS[wid];
    for (int grp = blockIdx.x * 16 + wid; grp * 4 < N_NODES; grp += wstride) {
        int r0 = grp * 4;
        const float4* xr = (const float4*)(x + (size_t)r0 * IN_C);
        ((float4*)xs)[lane]      = xr[lane];
        ((float4*)xs)[64 + lane] = xr[64 + lane];
        __builtin_amdgcn_wave_barrier();
        float a0x = 0, a0y = 0, a1x = 0, a1y = 0;
        float a2x = 0, a2y = 0, a3x = 0, a3y = 0;
        const float4* xs4 = (const float4*)xs;
#pragma unroll 4
        for (int k4 = 0; k4 < 32; ++k4) {
            float4 xv0 = xs4[k4];
            float4 xv1 = xs4[32 + k4];
            float4 xv2 = xs4[64 + k4];
            float4 xv3 = xs4[96 + k4];
            int k = k4 * 4;
            float2 w0 = WT2[(k + 0) * 65 + lane];
            float2 w1 = WT2[(k + 1) * 65 + lane];
            float2 w2 = WT2[(k + 2) * 65 + lane];
            float2 w3 = WT2[(k + 3) * 65 + lane];
#define ENC_ROW(ax, ay, xv)                                      \
            ax = fmaf(xv.x, w0.x, ax); ay = fmaf(xv.x, w0.y, ay); \
            ax = fmaf(xv.y, w1.x, ax); ay = fmaf(xv.y, w1.y, ay); \
            ax = fmaf(xv.z, w2.x, ax); ay = fmaf(xv.z, w2.y, ay); \
            ax = fmaf(xv.w, w3.x, ax); ay = fmaf(xv.w, w3.y, ay);
            ENC_ROW(a0x, a0y, xv0)
            ENC_ROW(a1x, a1y, xv1)
            ENC_ROW(a2x, a2y, xv2)
            ENC_ROW(a3x, a3y, xv3)
#undef ENC_ROW
        }
        __builtin_amdgcn_wave_barrier();
#define ENC_EPI(ax, ay, row)                                               \
        {                                                                   \
            float sum = ax + ay;                                            \
            for (int off = 32; off; off >>= 1) sum += __shfl_xor(sum, off); \
            float mu = sum * (1.0f / 128.0f);                               \
            float d0 = ax - mu, d1 = ay - mu;                               \
            float vs = d0 * d0 + d1 * d1;                                   \
            for (int off = 32; off; off >>= 1) vs += __shfl_xor(vs, off);   \
            float inv = rsqrtf(vs * (1.0f / 128.0f) + LN_EPS);              \
            float o0 = gelu_exact(gb.x * d0 * inv + bb.x);                  \
            float o1 = gelu_exact(gb.y * d1 * inv + bb.y);                  \
            H[(size_t)(row)*64 + lane] = pack_bf16_rne(o0, o1);             \
        }
        ENC_EPI(a0x, a0y, r0)
        ENC_EPI(a1x, a1y, r0 + 1)
        ENC_EPI(a2x, a2y, r0 + 2)
        ENC_EPI(a3x, a3y, r0 + 3)
#undef ENC_EPI
    }
}

// ---------------------------------------------------------------------------
// One APPNP step, phase-major chunked. Persistent wave owns NPW consecutive
// dst nodes (acc in registers, statically indexed). For chunk c = 0..15, all
// waves process their nodes' chunk-c edges -> concurrent gathers hit a ~1.6 MB
// moving window of z that fits per-XCD L2. Edge segments for (c, my nodes)
// are contiguous; edge params loaded cooperatively in 64-wide windows and
// shfl-broadcast. Gathers stay full 256 B rows. No padding (exact bounds).
__global__ __launch_bounds__(256, 4) void prop_k(
        const unsigned* __restrict__ zin, const unsigned* __restrict__ x0,
        const int* __restrict__ off2, const int2* __restrict__ ep,
        unsigned* __restrict__ zout, int fuse_ln,
        const float* __restrict__ gamma, const float* __restrict__ beta) {
    int W = (blockIdx.x * 256 + threadIdx.x) >> 6;    // wave id, 0..3999
    int lane = threadIdx.x & 63;
    int nbase = W * NPW;
    float ax[NPW], ay[NPW];
#pragma unroll
    for (int i = 0; i < NPW; ++i) { ax[i] = 0.f; ay[i] = 0.f; }
#pragma unroll 1
    for (int c = 0; c < NCHUNK; ++c) {
        int bidx = c * N_NODES + nbase;
        int bv = off2[bidx + min(lane, NPW)];          // 26 boundaries in lanes
        int E1 = __shfl(bv, NPW);
        int wbase = __shfl(bv, 0);
        int cursor = wbase;
        int cnt = min(64, E1 - wbase);
        int2 p = make_int2(0, 0);
        if (lane < cnt) p = ep[wbase + lane];
#pragma unroll
        for (int i = 0; i < NPW; ++i) {
            int eend = __shfl(bv, i + 1);
            while (cursor < eend) {
                int j = cursor - wbase;
                if (j >= cnt) {                        // reload window at cursor
                    wbase = cursor;
                    cnt = min(64, E1 - wbase);
                    p = make_int2(0, 0);
                    if (lane < cnt) p = ep[wbase + lane];
                    j = 0;
                }
                int px = __shfl(p.x, j);
                float w = __int_as_float(__shfl(p.y, j));
                unsigned v = zin[px + lane];           // 256 B row gather
                ax[i] = fmaf(w, bf_lo(v), ax[i]);
                ay[i] = fmaf(w, bf_hi(v), ay[i]);
                ++cursor;
            }
        }
    }
    // epilogue: z = alpha*x0 + acc; optional fused gelu+LN (last K-step)
    float2 gb = make_float2(0.f, 0.f), bb = make_float2(0.f, 0.f);
    if (fuse_ln) {
        gb = ((const float2*)gamma)[lane];
        bb = ((const float2*)beta)[lane];
    }
#pragma unroll
    for (int i = 0; i < NPW; ++i) {
        int n = nbase + i;
        unsigned xd = x0[(size_t)n * 64 + lane];
        float zx = fmaf(ALPHA, bf_lo(xd), ax[i]);
        float zy = fmaf(ALPHA, bf_hi(xd), ay[i]);
        unsigned od;
        if (fuse_ln) {
            float h0 = gelu_exact(zx), h1 = gelu_exact(zy);
            float sum = h0 + h1;
            for (int off = 32; off; off >>= 1) sum += __shfl_xor(sum, off);
            float mu = sum * (1.0f / 128.0f);
            float d0 = h0 - mu, d1 = h1 - mu;
            float vs = d0 * d0 + d1 * d1;
            for (int off = 32; off; off >>= 1) vs += __shfl_xor(vs, off);
            float inv = rsqrtf(vs * (1.0f / 128.0f) + LN_EPS);
            od = pack_bf16_rne(gb.x * d0 * inv + bb.x, gb.y * d1 * inv + bb.y);
        } else {
            od = pack_bf16_rne(zx, zy);
        }
        zout[(size_t)n * 64 + lane] = od;
    }
}

// ---------------------------------------------------------------------------
// Decoder: out(fp32) = H(bf16) @ Wdec^T -> [N, 64].  (proven R5 structure)
__global__ __launch_bounds__(1024) void decoder_k(
        const unsigned* __restrict__ H, const float* __restrict__ Wdec,
        float* __restrict__ out) {
    __shared__ float WT[HID_C * 65];
    __shared__ unsigned XS[16][256];
    for (int i = threadIdx.x; i < OUT_C * HID_C; i += 1024) {
        int o = i >> 7, k = i & 127;
        WT[k * 65 + o] = Wdec[i];
    }
    __syncthreads();
    int lane = threadIdx.x & 63;
    int wid  = threadIdx.x >> 6;
    int wstride = gridDim.x * 16;
    unsigned* xs = XS[wid];
    for (int grp = blockIdx.x * 16 + wid; grp * 4 < N_NODES; grp += wstride) {
        int r0 = grp * 4;
        const unsigned* hp = H + (size_t)r0 * 64;
        xs[lane]       = hp[lane];
        xs[64 + lane]  = hp[64 + lane];
        xs[128 + lane] = hp[128 + lane];
        xs[192 + lane] = hp[192 + lane];
        __builtin_amdgcn_wave_barrier();
        float a0 = 0, a1 = 0, a2 = 0, a3 = 0;
#pragma unroll 4
        for (int k2 = 0; k2 < 64; ++k2) {
            float w0 = WT[(2 * k2) * 65 + lane];
            float w1 = WT[(2 * k2 + 1) * 65 + lane];
            unsigned u0 = xs[k2];
            unsigned u1 = xs[64 + k2];
            unsigned u2 = xs[128 + k2];
            unsigned u3 = xs[192 + k2];
            a0 = fmaf(bf_lo(u0), w0, a0); a0 = fmaf(bf_hi(u0), w1, a0);
            a1 = fmaf(bf_lo(u1), w0, a1); a1 = fmaf(bf_hi(u1), w1, a1);
            a2 = fmaf(bf_lo(u2), w0, a2); a2 = fmaf(bf_hi(u2), w1, a2);
            a3 = fmaf(bf_lo(u3), w0, a3); a3 = fmaf(bf_hi(u3), w1, a3);
        }
        __builtin_amdgcn_wave_barrier();
        out[(size_t)r0 * OUT_C + lane]       = a0;
        out[(size_t)(r0 + 1) * OUT_C + lane] = a1;
        out[(size_t)(r0 + 2) * OUT_C + lane] = a2;
        out[(size_t)(r0 + 3) * OUT_C + lane] = a3;
    }
}

// ---------------------------------------------------------------------------
extern "C" void kernel_launch(void* const* d_in, const int* in_sizes, int n_in,
                              void* d_out, int out_size, void* d_ws, size_t ws_size,
                              hipStream_t stream) {
    const float* x     = (const float*)d_in[0];
    const int*   ei    = (const int*)d_in[1];
    const float* ew    = (const float*)d_in[2];
    const float* Wenc  = (const float*)d_in[3];
    const float* Wdec  = (const float*)d_in[4];
    const float* gamma = (const float*)d_in[5];
    const float* beta  = (const float*)d_in[6];
    float* out = (float*)d_out;

    const int* src = ei;
    const int* dst = ei + N_EDGES;

    char* p = (char*)d_ws;
    auto carve = [&](size_t bytes) -> void* {
        void* r = (void*)p;
        p += (bytes + 255) & ~(size_t)255;
        return r;
    };
    int*  cnt2  = (int*)carve((size_t)M2 * sizeof(int));
    int*  fill2 = (int*)carve((size_t)(M2 + 1) * sizeof(int));
    int*  off2  = (int*)carve((size_t)(M2 + 1) * sizeof(int));
    int*  bsum  = (int*)carve(S2_BLOCKS * sizeof(int));
    int2* ep    = (int2*)carve((size_t)N_EDGES * sizeof(int2));
    unsigned* H  = (unsigned*)carve((size_t)N_NODES * 64 * sizeof(unsigned));
    unsigned* ZA = (unsigned*)carve((size_t)N_NODES * 64 * sizeof(unsigned));
    unsigned* ZB = (unsigned*)carve((size_t)N_NODES * 64 * sizeof(unsigned));

    // Build (chunk,dst)-major CSR (per launch; deterministic)
    hipMemsetAsync(cnt2, 0, (size_t)M2 * sizeof(int), stream);
    count2_k<<<(N_EDGES + 255) / 256, 256, 0, stream>>>(src, dst, cnt2);
    scan1_k<<<S2_BLOCKS, 1024, 0, stream>>>(cnt2, bsum);
    scan2_k<<<1, 1024, 0, stream>>>(bsum);
    scan3_k<<<S2_BLOCKS, 1024, 0, stream>>>(cnt2, bsum, off2, fill2);
    bucket2_k<<<(N_EDGES + 255) / 256, 256, 0, stream>>>(src, dst, ew, fill2, ep);

    // Encoder
    encoder_k<<<512, 1024, 0, stream>>>(x, Wenc, gamma, beta, H);

    unsigned* bufs[2] = {ZA, ZB};
    for (int l = 0; l < NLAYERS; ++l) {
        const unsigned* zin = H;                  // x0 = H (layer input)
        for (int k = 0; k < KSTEPS; ++k) {
            int last = (k == KSTEPS - 1);
            unsigned* zout = last ? H : bufs[k & 1];
            prop_k<<<PROP_BLOCKS, 256, 0, stream>>>(zin, H, off2, ep, zout,
                                                    last, gamma, beta);
            zin = zout;
        }
    }

    decoder_k<<<512, 1024, 0, stream>>>(H, Wdec, out);
}